// Round 6
// baseline (51.567 us; speedup 1.0000x reference)
//
#include <hip/hip_runtime.h>
#include <hip/hip_fp16.h>

#define N_NODES 100000
#define N_EDGES 600000
#define DIM 128
#define HID 64
#define NTILES 6250          // 100000 / 16 exact

typedef __attribute__((ext_vector_type(8))) _Float16 half8;
typedef __attribute__((ext_vector_type(4))) _Float16 half4v;
typedef __attribute__((ext_vector_type(4))) float floatx4;

#define VMCNT(n) asm volatile("s_waitcnt vmcnt(" #n ")" ::: "memory")

// direct global -> LDS; LDS dest is wave-uniform base, HW adds lane*16.
__device__ __forceinline__ void gload_lds16(const void* g, void* l) {
    __builtin_amdgcn_global_load_lds(
        (const __attribute__((address_space(1))) void*)g,
        (__attribute__((address_space(3))) void*)l, 16, 0, 0);
}

// ---------------------------------------------------------------------------
// Kernel 0: W1T[c][k] (f16, [128][128]) = c<64 ? W1[k][c] : W1[128+k][c-64]
// ---------------------------------------------------------------------------
__global__ __launch_bounds__(256) void prep_W(
    const float* __restrict__ W1, __half* __restrict__ W1T)
{
    const int o = (int)(blockIdx.x * blockDim.x + threadIdx.x) * 2;
    if (o >= 128 * 128) return;
    const int c = o >> 7, k = o & 127;
    float w0, w1;
    if (c < HID) { w0 = W1[k * HID + c];               w1 = W1[(k + 1) * HID + c]; }
    else         { w0 = W1[(DIM + k) * HID + c - HID]; w1 = W1[(DIM + k + 1) * HID + c - HID]; }
    W1T[o]     = __float2half(w0);
    W1T[o + 1] = __float2half(w1);
}

// ---------------------------------------------------------------------------
// Kernel 1: P = node_emb @ Wbig (+b1 on hidden 0..63), f16 out, permuted
// epilogue (as R5). Wave-autonomous: each wave owns 2x8KB LDS, pipelines
// 16-row tiles via global_load_lds, no barriers. Per-block contiguous quota
// (12 or 13 tiles) spreads the remainder across distinct CUs.
// ---------------------------------------------------------------------------
__global__ __launch_bounds__(256, 2) void precompute_P(
    const float* __restrict__ node_emb,
    const __half* __restrict__ W1T,
    const float* __restrict__ b1,
    __half* __restrict__ P)
{
    __shared__ char lds[4][2][8192];     // [wave][buf][16 rows x 512 B]

    const int tid  = threadIdx.x;
    const int w    = tid >> 6;
    const int lane = tid & 63;
    const int lr   = lane & 15;
    const int q    = lane >> 4;

    // W fragments -> regs (32 x 16B loads; drained by the first VMCNT)
    half8 wf[8][4];
#pragma unroll
    for (int nt = 0; nt < 8; nt++)
#pragma unroll
        for (int ks = 0; ks < 4; ks++)
            wf[nt][ks] = *(const half8*)(W1T + (size_t)(nt * 16 + lr) * 128 + ks * 32 + q * 8);

    float bias_[4][4];
#pragma unroll
    for (int nt = 0; nt < 4; nt++) {
        const float4 b4 = *(const float4*)(b1 + nt * 16 + q * 4);
        bias_[nt][0] = b4.x; bias_[nt][1] = b4.y;
        bias_[nt][2] = b4.z; bias_[nt][3] = b4.w;
    }

    const int b     = (int)blockIdx.x;
    const int base  = b * 12 + (b < 106 ? b : 106);
    const int quota = 12 + (b < 106 ? 1 : 0);

    const char* nb = (const char*)node_emb;
    char* const bufs[2] = { &lds[w][0][0], &lds[w][1][0] };

    const int rhalf = lane >> 5;              // staging: row parity within pair
    const int in16  = (lane & 31) << 4;       // staging: byte within row

    // stage tile t (rows 16t..16t+15) into wave-private buffer
#define STAGE(T, BUF)                                                        \
    {                                                                        \
        _Pragma("unroll")                                                    \
        for (int r = 0; r < 8; r++) {                                        \
            const int row_in = 2 * r + rhalf;                                \
            const size_t src = (size_t)((T) * 16 + row_in) * 512             \
                             + (size_t)(in16 ^ ((row_in & 7) << 4));         \
            gload_lds16(nb + src, (BUF) + r * 1024);                         \
        }                                                                    \
    }

    int i  = w;
    int tA = (i     < quota) ? base + i     : -1;
    int tB = (i + 4 < quota) ? base + i + 4 : -1;
    int nexti = i + 8;

    if (tA >= 0) STAGE(tA, bufs[0]);
    if (tB >= 0) STAGE(tB, bufs[1]);

    int cur = 0;
    bool first = true;
    while (tA >= 0) {
        // wait for tA's 8 loads (in-order vmcnt; stores count too)
        if (first) { if (tB >= 0) VMCNT(8);  else VMCNT(0); }
        else       { if (tB >= 0) VMCNT(12); else VMCNT(4); }

        // compute 16-row tile from bufs[cur]
        floatx4 acc[8];
#pragma unroll
        for (int nt = 0; nt < 8; nt++) acc[nt] = (floatx4){0.f, 0.f, 0.f, 0.f};

        const char* Ab = bufs[cur];
        const int sw = (lr & 7) << 4;
#pragma unroll
        for (int ks = 0; ks < 4; ks++) {
            const int cb = ks * 128 + q * 32;
            const float4 x0 = *(const float4*)(Ab + lr * 512 + ((cb)      ^ sw));
            const float4 x1 = *(const float4*)(Ab + lr * 512 + ((cb + 16) ^ sw));
            half8 af;
            af[0] = (_Float16)x0.x; af[1] = (_Float16)x0.y;
            af[2] = (_Float16)x0.z; af[3] = (_Float16)x0.w;
            af[4] = (_Float16)x1.x; af[5] = (_Float16)x1.y;
            af[6] = (_Float16)x1.z; af[7] = (_Float16)x1.w;
#pragma unroll
            for (int nt = 0; nt < 8; nt++)
                acc[nt] = __builtin_amdgcn_mfma_f32_16x16x32_f16(wf[nt][ks], af, acc[nt], 0, 0, 0);
        }

        // all ds_reads retired before we overwrite this buffer
        asm volatile("s_waitcnt lgkmcnt(0)" ::: "memory");
        __builtin_amdgcn_sched_barrier(0);

        const int tC = (nexti < quota) ? base + nexti : -1;
        if (tC >= 0) STAGE(tC, bufs[cur]);          // 8 loads, before stores

        // permuted packed epilogue: 4 x 16B stores
        {
            char* prow = (char*)P + (size_t)(tA * 16 + lr) * 256;
#pragma unroll
            for (int m = 0; m < 4; m++) {
                half8 hh;
#pragma unroll
                for (int ii = 0; ii < 4; ii++) {
                    float va = acc[2 * m][ii];
                    float vb = acc[2 * m + 1][ii];
                    if (m < 2) { va += bias_[2 * m][ii]; vb += bias_[2 * m + 1][ii]; }
                    hh[ii]     = (_Float16)va;
                    hh[ii + 4] = (_Float16)vb;
                }
                *(half8*)(prow + m * 64 + q * 16) = hh;
            }
        }

        tA = tB; tB = tC; nexti += 4; cur ^= 1; first = false;
    }
#undef STAGE
}

// ---------------------------------------------------------------------------
__device__ inline bool detect_int64(const int* e32) {
    int orv = 0;
#pragma unroll
    for (int k = 0; k < 8; k++) orv |= e32[2 * k + 1];
    return orv == 0;
}

// ---------------------------------------------------------------------------
// Kernel 2: quarter-wave (16 lanes) per edge; lane j holds P-positions
// 4j..4j+3 (permuted hidden units). W2 read through the inverse permutation.
// ---------------------------------------------------------------------------
__global__ __launch_bounds__(256) void edge_mlp(
    const __half* __restrict__ P,
    const void* __restrict__ eidx_raw,
    const float* __restrict__ W2,
    const float* __restrict__ b2,
    float* __restrict__ out)
{
    const int* e32 = (const int*)eidx_raw;
    const long long* e64 = (const long long*)eidx_raw;
    const bool is64 = detect_int64(e32);

    const int tid  = threadIdx.x;
    const int lane = tid & 63;
    const int j    = lane & 15;
    const int grp  = lane >> 4;
    const int hbase = ((j >> 3) << 5) + ((j & 1) << 4) + (((j >> 1) & 3) << 2);
    const float4 w2 = *(const float4*)(W2 + hbase);
    const float b2v = b2[0];

    const int gwid   = (int)((blockIdx.x * blockDim.x + tid) >> 6);
    const int nwaves = (int)((gridDim.x * blockDim.x) >> 6);

    const half4v zero = {(_Float16)0, (_Float16)0, (_Float16)0, (_Float16)0};

    for (int base = gwid * 16; base < N_EDGES; base += nwaves * 16) {
        int s[4], d[4];
#pragma unroll
        for (int u = 0; u < 4; u++) {
            const int e = base + 4 * u + grp;
            if (is64) { s[u] = (int)e64[e]; d[u] = (int)e64[N_EDGES + e]; }
            else      { s[u] = e32[e];      d[u] = e32[N_EDGES + e]; }
        }
        half4v av[4], bv[4];
#pragma unroll
        for (int u = 0; u < 4; u++) {
            av[u] = *(const half4v*)(P + (size_t)s[u] * 128 + 4 * j);
            bv[u] = *(const half4v*)(P + (size_t)d[u] * 128 + 64 + 4 * j);
        }
#pragma unroll
        for (int u = 0; u < 4; u++) {
            const half4v t = av[u] + bv[u];                    // v_pk_add_f16
            const half4v r = __builtin_elementwise_max(t, zero);
            float acc = (float)r[0] * w2.x + (float)r[1] * w2.y
                      + (float)r[2] * w2.z + (float)r[3] * w2.w;
#pragma unroll
            for (int off = 8; off >= 1; off >>= 1)
                acc += __shfl_xor(acc, off, 64);
            if (j == 0) out[base + 4 * u + grp] = acc + b2v;
        }
    }
}

// ---------------------------------------------------------------------------
// Fallback (ws too small): direct per-edge compute, slow but correct.
// ---------------------------------------------------------------------------
__global__ __launch_bounds__(256) void edge_mlp_direct(
    const float* __restrict__ node_emb,
    const void* __restrict__ eidx_raw,
    const float* __restrict__ W1,
    const float* __restrict__ b1,
    const float* __restrict__ W2,
    const float* __restrict__ b2,
    float* __restrict__ out)
{
    const int* e32 = (const int*)eidx_raw;
    const long long* e64 = (const long long*)eidx_raw;
    const bool is64 = detect_int64(e32);

    const int lane = threadIdx.x & 63;
    const float w2  = W2[lane];
    const float b2v = b2[0];
    const int gwid   = (int)((blockIdx.x * blockDim.x + threadIdx.x) >> 6);
    const int nwaves = (int)((gridDim.x * blockDim.x) >> 6);

    for (int e = gwid; e < N_EDGES; e += nwaves) {
        int s, d;
        if (is64) { s = (int)e64[e]; d = (int)e64[N_EDGES + e]; }
        else      { s = e32[e];      d = e32[N_EDGES + e]; }
        const float* es = node_emb + (size_t)s * DIM;
        const float* ed = node_emb + (size_t)d * DIM;
        float acc = b1[lane];
        for (int k = 0; k < DIM; k++) {
            acc += es[k] * W1[k * HID + lane];
            acc += ed[k] * W1[(DIM + k) * HID + lane];
        }
        float t = fmaxf(acc, 0.f) * w2;
#pragma unroll
        for (int off = 32; off >= 1; off >>= 1)
            t += __shfl_xor(t, off, 64);
        if (lane == 0) out[e] = t + b2v;
    }
}

// ---------------------------------------------------------------------------
extern "C" void kernel_launch(void* const* d_in, const int* in_sizes, int n_in,
                              void* d_out, int out_size, void* d_ws, size_t ws_size,
                              hipStream_t stream) {
    const float* node_emb = (const float*)d_in[0];
    const void*  eidx     = d_in[1];
    const float* W1       = (const float*)d_in[2];
    const float* b1       = (const float*)d_in[3];
    const float* W2       = (const float*)d_in[4];
    const float* b2       = (const float*)d_in[5];
    float* out = (float*)d_out;

    const size_t wt_off = 32u * 1024 * 1024;
    const size_t need   = wt_off + 128 * 128 * sizeof(__half);

    if (ws_size >= need) {
        __half* P   = (__half*)d_ws;
        __half* W1T = (__half*)((char*)d_ws + wt_off);
        prep_W<<<32, 256, 0, stream>>>(W1, W1T);
        precompute_P<<<512, 256, 0, stream>>>(node_emb, W1T, b1, P);
        edge_mlp<<<2048, 256, 0, stream>>>(P, eidx, W2, b2, out);
    } else {
        edge_mlp_direct<<<4096, 256, 0, stream>>>(node_emb, eidx, W1, b1, W2, b2, out);
    }
}